// Round 20
// baseline (257.442 us; speedup 1.0000x reference)
//
#include <hip/hip_runtime.h>
#include <cstdint>

#define NROWS 16384
#define GRID 256

typedef __attribute__((ext_vector_type(4))) float f32x4;
typedef _Float16 half8 __attribute__((ext_vector_type(8)));
typedef unsigned int u32x4 __attribute__((ext_vector_type(4)));

static __device__ __forceinline__ void gl_lds16(const void* g, void* l) {
  __builtin_amdgcn_global_load_lds(
      (const __attribute__((address_space(1))) unsigned int*)g,
      (__attribute__((address_space(3))) unsigned int*)l, 16, 0, 0);
}

// device-scope grid barrier; bar[g] zeroed by host memset each launch
static __device__ __forceinline__ void gbar(unsigned* bar, int g) {
  __syncthreads();
  if (threadIdx.x == 0) {
    __threadfence();
    atomicAdd(&bar[g], 1u);
    while (atomicAdd(&bar[g], 0u) < (unsigned)GRID) __builtin_amdgcn_s_sleep(1);
  }
  __syncthreads();
  __threadfence();
}

struct TR { u32x4 q0a, a0, a1, a2, a3, b0, b1, b2, b3,
                  q0b, c0, c1, c2, c3, d0, d1, d2, d3; };

#define WAITV(n) do { \
  asm volatile("s_waitcnt vmcnt(" #n ")" ::: "memory"); \
  __builtin_amdgcn_sched_barrier(0); \
} while (0)

#define MFMA4(avx, B0, B1, B2, B3, mb) do { \
  acc[mb][0] = __builtin_amdgcn_mfma_f32_16x16x32_f16(avx, __builtin_bit_cast(half8, B0), acc[mb][0], 0, 0, 0); \
  acc[mb][1] = __builtin_amdgcn_mfma_f32_16x16x32_f16(avx, __builtin_bit_cast(half8, B1), acc[mb][1], 0, 0, 0); \
  acc[mb][2] = __builtin_amdgcn_mfma_f32_16x16x32_f16(avx, __builtin_bit_cast(half8, B2), acc[mb][2], 0, 0, 0); \
  acc[mb][3] = __builtin_amdgcn_mfma_f32_16x16x32_f16(avx, __builtin_bit_cast(half8, B3), acc[mb][3], 0, 0, 0); \
} while (0)

#define COMPUTE2(T) do { \
  half8 _q0 = __builtin_bit_cast(half8, T.q0a); \
  half8 _av; \
  _av = _q0 * __builtin_bit_cast(half8, T.a0); MFMA4(_av, T.b0, T.b1, T.b2, T.b3, 0); \
  _av = _q0 * __builtin_bit_cast(half8, T.a1); MFMA4(_av, T.b0, T.b1, T.b2, T.b3, 1); \
  _av = _q0 * __builtin_bit_cast(half8, T.a2); MFMA4(_av, T.b0, T.b1, T.b2, T.b3, 2); \
  _av = _q0 * __builtin_bit_cast(half8, T.a3); MFMA4(_av, T.b0, T.b1, T.b2, T.b3, 3); \
  _q0 = __builtin_bit_cast(half8, T.q0b); \
  _av = _q0 * __builtin_bit_cast(half8, T.c0); MFMA4(_av, T.d0, T.d1, T.d2, T.d3, 0); \
  _av = _q0 * __builtin_bit_cast(half8, T.c1); MFMA4(_av, T.d0, T.d1, T.d2, T.d3, 1); \
  _av = _q0 * __builtin_bit_cast(half8, T.c2); MFMA4(_av, T.d0, T.d1, T.d2, T.d3, 2); \
  _av = _q0 * __builtin_bit_cast(half8, T.c3); MFMA4(_av, T.d0, T.d1, T.d2, T.d3, 3); \
  __builtin_amdgcn_sched_barrier(0); \
} while (0)

__global__ __launch_bounds__(512, 1) void vq_fused(
    const float* __restrict__ x, const float* __restrict__ emb,
    const float* __restrict__ prior,
    unsigned short* __restrict__ qbf, float* __restrict__ cpart,
    float* __restrict__ ppart, float* __restrict__ ghist_part,
    double* __restrict__ gmse_part, float* __restrict__ hcond,
    float* __restrict__ Cpair, float* __restrict__ hsumg,
    double* __restrict__ gmseg, unsigned* __restrict__ bar,
    float* __restrict__ quant, float* __restrict__ loss_out)
{
  __shared__ __align__(16) char smem[98304];
  const int tid = threadIdx.x;
  const int w = tid >> 6, lane = tid & 63;
  const int bx = blockIdx.x;

  // ================= P1: distances/argmin/softmax/quantize + image build =================
  {
    float (*Et4)[64][4] = (float(*)[64][4])(smem);            // 32768
    float (*xs)[4][128] = (float(*)[4][128])(smem + 32768);   // 16384
    float (*qlds)[65]   = (float(*)[65])(smem + 49152);       // 17160
    float* lhist        = (float*)(smem + 66560);             // 256
    double* mred        = (double*)(smem + 66816);            // 64

    const int c = bx;
    for (int i = tid; i < 2048; i += 512) {
      float4 v = ((const float4*)emb)[i];
      *(float4*)&Et4[i & 31][i >> 5][0] = v;
    }
    if (tid < 64) lhist[tid] = 0.0f;
    __syncthreads();

    double esq = 0.0;
    for (int g = 0; g < 32; ++g) {
      float4 e = *(float4*)&Et4[g][lane][0];
      esq += (double)e.x*e.x + (double)e.y*e.y + (double)e.z*e.z + (double)e.w*e.w;
    }
    const float esqf = (float)esq;
    double msea = 0.0;

    for (int it = 0; it < 3; ++it) {
      const int lr0 = it*32 + w*4;
      const bool act = (it < 2) || (w == 0);
      if (!act) continue;
      const int nr = (it < 2) ? 4 : 2;
      const int r0 = c*64 + lr0;
      const float4* xg = (const float4*)(x + (size_t)r0 * 128);
      if (it < 2) {
        float4 v0 = xg[lane], v1 = xg[lane + 64];
        *(float4*)&xs[w][lane>>5][(lane&31)<<2] = v0;
        *(float4*)&xs[w][2+(lane>>5)][(lane&31)<<2] = v1;
      } else {
        int rr = lane >> 5;
        float4 v0 = make_float4(0.f,0.f,0.f,0.f);
        if (r0 + rr < NROWS) v0 = xg[lane];
        *(float4*)&xs[w][rr][(lane&31)<<2] = v0;
      }

      float accf[4] = {0.f,0.f,0.f,0.f};
      for (int g = 0; g < 32; ++g) {
        float4 e = *(float4*)&Et4[g][lane][0];
        #pragma unroll
        for (int rr = 0; rr < 4; ++rr) {
          float4 xv = *(float4*)&xs[w][rr][g<<2];
          accf[rr] += e.x*xv.x + e.y*xv.y + e.z*xv.z + e.w*xv.w;
        }
      }

      for (int rr = 0; rr < nr; ++rr) {
        float dist = esqf - 2.0f*accf[rr];
        float mx = dist;
        #pragma unroll
        for (int off = 32; off; off >>= 1) mx = fmaxf(mx, __shfl_xor(mx, off));
        float sh = dist - mx;
        float ss = expf(sh);
        #pragma unroll
        for (int off = 32; off; off >>= 1) ss += __shfl_xor(ss, off);
        qlds[lr0 + rr][lane] = sh - logf(ss);

        if (it < 2) {
          float m1 = dist, m2 = 3.4e38f; int i1 = lane;
          #pragma unroll
          for (int off = 32; off; off >>= 1) {
            float om1 = __shfl_xor(m1, off);
            int   oi1 = __shfl_xor(i1, off);
            float om2 = __shfl_xor(m2, off);
            float nm2 = fminf(m2, om2);
            if (om1 < m1 || (om1 == m1 && oi1 < i1)) { nm2 = fminf(nm2, m1); m1 = om1; i1 = oi1; }
            else nm2 = fminf(nm2, om1);
            m2 = nm2;
          }
          int bi = i1;
          if (m2 - m1 < 1e-4f) {
            double a64 = 0.0;
            for (int g = 0; g < 32; ++g) {
              float4 e = *(float4*)&Et4[g][lane][0];
              float4 xv = *(float4*)&xs[w][rr][g<<2];
              a64 += (double)e.x*xv.x + (double)e.y*xv.y + (double)e.z*xv.z + (double)e.w*xv.w;
            }
            double v = esq - 2.0*a64; int b2 = lane;
            #pragma unroll
            for (int off = 32; off; off >>= 1) {
              double ov = __shfl_xor(v, off);
              int ob = __shfl_xor(b2, off);
              if (ov < v || (ov == v && ob < b2)) { v = ov; b2 = ob; }
            }
            bi = b2;
          }
          const int row = r0 + rr;
          float e0 = emb[bi*128 + lane], e1 = emb[bi*128 + 64 + lane];
          float x0 = xs[w][rr][lane], x1 = xs[w][rr][64 + lane];
          quant[(size_t)row*128 + lane]      = x0 + (e0 - x0);
          quant[(size_t)row*128 + 64 + lane] = x1 + (e1 - x1);
          double d0 = (double)e0 - x0, d1 = (double)e1 - x1;
          msea += d0*d0 + d1*d1;
          if (lane == 0) atomicAdd(&lhist[bi], 1.0f);
        }
      }
    }
    #pragma unroll
    for (int off = 32; off; off >>= 1) msea += __shfl_down(msea, off);
    if (lane == 0) mred[w] = msea;
    __syncthreads();
    if (tid == 0) {
      double s = 0.0;
      #pragma unroll
      for (int j = 0; j < 8; ++j) s += mred[j];
      gmse_part[c] = s;
    }
    if (tid < 64) ghist_part[(c << 6) + tid] = lhist[tid];

    char* out0 = (char*)qbf + (size_t)c * 24576;
    for (int idx = tid; idx < 1536; idx += 512) {
      int s = idx >> 9, kk = (idx >> 3) & 63, t8 = (idx & 7) << 3;
      union { _Float16 h[8]; uint4 u; } pk;
      #pragma unroll
      for (int j = 0; j < 8; ++j) {
        int tt = t8 + j, t = c*64 + tt;
        float val = qlds[tt + s][kk];
        bool zero = (s == 1 && (t & 4095) == 4095) || (s == 2 && (t & 4095) >= 4094);
        pk.h[j] = (_Float16)(zero ? 0.0f : val);
      }
      int off;
      if (s == 0) off = kk*128 + t8*2;
      else off = s*8192 + (((kk >> 4) << 1) + (t8 >> 5))*1024 + ((kk & 15) | (((t8 >> 3) & 3) << 4))*16;
      *(uint4*)(out0 + off) = pk.u;
    }
  }

  gbar(bar, 0);

  // ================= P2a: C partials (waves 0-3, gl_lds 4-buffer pipeline) =================
  {
    char* ldsb = smem;                 // 4 x 24576
    const char* qb = (const char*)qbf;
    if (w < 4) {
      const int kg = bx >> 4, chunk = bx & 15;
      const int k = kg*4 + w;
      const int lf = lane * 16;
      const int voff_q0a = (k << 7) + ((lane >> 4) << 4);
      const int voff_q0b = voff_q0a + 64;
      const int voff_a0 = 8192  + 0*2048 + lf;
      const int voff_a1 = 8192  + 1*2048 + lf;
      const int voff_a2 = 8192  + 2*2048 + lf;
      const int voff_a3 = 8192  + 3*2048 + lf;
      const int voff_b0 = 16384 + 0*2048 + lf;
      const int voff_b1 = 16384 + 1*2048 + lf;
      const int voff_b2 = 16384 + 2*2048 + lf;
      const int voff_b3 = 16384 + 3*2048 + lf;
      const int voff_c0 = 8192  + 0*2048 + 1024 + lf;
      const int voff_c1 = 8192  + 1*2048 + 1024 + lf;
      const int voff_c2 = 8192  + 2*2048 + 1024 + lf;
      const int voff_c3 = 8192  + 3*2048 + 1024 + lf;
      const int voff_d0 = 16384 + 0*2048 + 1024 + lf;
      const int voff_d1 = 16384 + 1*2048 + 1024 + lf;
      const int voff_d2 = 16384 + 2*2048 + 1024 + lf;
      const int voff_d3 = 16384 + 3*2048 + 1024 + lf;

      f32x4 acc[4][4];
      #pragma unroll
      for (int i = 0; i < 4; ++i)
        #pragma unroll
        for (int j = 0; j < 4; ++j) acc[i][j] = (f32x4)(0.f);

      const int t0 = chunk * 16;

#define STAGE(t, b) do { \
  const char* _s = qb + (size_t)(t0 + (t)) * 24576 + tid*16; \
  char* _d = ldsb + (size_t)(b)*24576 + tid*16; \
  gl_lds16(_s + 0*4096, _d + 0*4096); \
  gl_lds16(_s + 1*4096, _d + 1*4096); \
  gl_lds16(_s + 2*4096, _d + 2*4096); \
  gl_lds16(_s + 3*4096, _d + 3*4096); \
  gl_lds16(_s + 4*4096, _d + 4*4096); \
  gl_lds16(_s + 5*4096, _d + 5*4096); \
} while (0)

#define LDSCOMP(b) do { \
  const char* _L = ldsb + (size_t)(b)*24576; \
  TR T; \
  T.q0a = *(const u32x4*)(_L + voff_q0a); \
  T.q0b = *(const u32x4*)(_L + voff_q0b); \
  T.a0  = *(const u32x4*)(_L + voff_a0); \
  T.a1  = *(const u32x4*)(_L + voff_a1); \
  T.a2  = *(const u32x4*)(_L + voff_a2); \
  T.a3  = *(const u32x4*)(_L + voff_a3); \
  T.b0  = *(const u32x4*)(_L + voff_b0); \
  T.b1  = *(const u32x4*)(_L + voff_b1); \
  T.b2  = *(const u32x4*)(_L + voff_b2); \
  T.b3  = *(const u32x4*)(_L + voff_b3); \
  T.c0  = *(const u32x4*)(_L + voff_c0); \
  T.c1  = *(const u32x4*)(_L + voff_c1); \
  T.c2  = *(const u32x4*)(_L + voff_c2); \
  T.c3  = *(const u32x4*)(_L + voff_c3); \
  T.d0  = *(const u32x4*)(_L + voff_d0); \
  T.d1  = *(const u32x4*)(_L + voff_d1); \
  T.d2  = *(const u32x4*)(_L + voff_d2); \
  T.d3  = *(const u32x4*)(_L + voff_d3); \
  COMPUTE2(T); \
} while (0)

#define STEP_MID(i) do { \
  STAGE((i)+2, ((i)+2)&3); \
  WAITV(12); \
  __builtin_amdgcn_s_barrier(); \
  LDSCOMP((i)&3); \
} while (0)

      STAGE(0, 0);
      STAGE(1, 1);
      STEP_MID(0);  STEP_MID(1);  STEP_MID(2);  STEP_MID(3);
      STEP_MID(4);  STEP_MID(5);  STEP_MID(6);  STEP_MID(7);
      STEP_MID(8);  STEP_MID(9);  STEP_MID(10); STEP_MID(11);
      STEP_MID(12); STEP_MID(13);
      WAITV(6);
      __builtin_amdgcn_s_barrier();
      LDSCOMP(14 & 3);
      WAITV(0);
      __builtin_amdgcn_s_barrier();
      LDSCOMP(15 & 3);
#undef STEP_MID
#undef LDSCOMP
#undef STAGE

      float* Ck = cpart + ((size_t)chunk*64 + (size_t)k) * 4096;
      const int m0 = (lane >> 4) << 2, n0 = lane & 15;
      #pragma unroll
      for (int mb = 0; mb < 4; ++mb)
        #pragma unroll
        for (int nb = 0; nb < 4; ++nb)
          #pragma unroll
          for (int r = 0; r < 4; ++r)
            Ck[(mb*16 + m0 + r)*64 + nb*16 + n0] = acc[mb][nb][r];
    } else {
      #pragma unroll 1
      for (int i = 0; i < 16; ++i) __builtin_amdgcn_s_barrier();
    }

    // ---------- P2b: C_pair partials on blocks 0..15 (8 waves) ----------
    if (bx < 16) {
      __syncthreads();
      float* redf = (float*)smem;      // 16KB, ldsb dead now
      for (int i = tid; i < 4096; i += 512) redf[i] = 0.f;
      __syncthreads();

      f32x4 acc[4][4];
      #pragma unroll
      for (int i = 0; i < 4; ++i)
        #pragma unroll
        for (int j = 0; j < 4; ++j) acc[i][j] = (f32x4)(0.f);

      for (int ii = 0; ii < 2; ++ii) {
        const char* tp = qb + (size_t)(bx*16 + w*2 + ii) * 24576;
        #pragma unroll
        for (int s = 0; s < 2; ++s) {
          half8 Av[4], Bv[4];
          #pragma unroll
          for (int mb = 0; mb < 4; ++mb)
            Av[mb] = *(const half8*)(tp + (mb*16 + (lane & 15))*128 + ((lane >> 4) << 4) + s*64);
          #pragma unroll
          for (int nb = 0; nb < 4; ++nb)
            Bv[nb] = *(const half8*)(tp + 8192 + (nb*2 + s)*1024 + lane*16);
          #pragma unroll
          for (int mb = 0; mb < 4; ++mb)
            #pragma unroll
            for (int nb = 0; nb < 4; ++nb)
              acc[mb][nb] = __builtin_amdgcn_mfma_f32_16x16x32_f16(Av[mb], Bv[nb], acc[mb][nb], 0, 0, 0);
        }
      }
      __syncthreads();
      const int m0 = (lane >> 4) << 2, n0 = lane & 15;
      #pragma unroll
      for (int mb = 0; mb < 4; ++mb)
        #pragma unroll
        for (int nb = 0; nb < 4; ++nb)
          #pragma unroll
          for (int r = 0; r < 4; ++r)
            atomicAdd(&redf[(mb*16 + m0 + r)*64 + nb*16 + n0], acc[mb][nb][r]);
      __syncthreads();
      float* dst = ppart + (size_t)bx * 4096;
      for (int i = tid; i < 4096; i += 512) dst[i] = redf[i];
    }
  }

  gbar(bar, 1);

  // ================= P3: hcond rows + Cpair reduce + hist/mse =================
  {
    float (*srow)[68] = (float(*)[68])smem;        // 4352 B
    float (*hpart)[64] = (float(*)[64])(smem + 4608);
    double* dred = (double*)(smem + 6656);

    const int k = bx >> 2, mq = bx & 3;
    f32x4 a[2];
    a[0] = (f32x4)(0.f); a[1] = (f32x4)(0.f);
    #pragma unroll
    for (int cc = 0; cc < 16; ++cc) {
      const f32x4* src = (const f32x4*)(cpart + (size_t)cc*262144 + (size_t)k*4096 + mq*1024);
      #pragma unroll
      for (int j = 0; j < 2; ++j) a[j] += src[tid + j*512];
    }
    #pragma unroll
    for (int j = 0; j < 2; ++j) {
      int e = (tid + j*512) * 4;
      *(f32x4*)&srow[e >> 6][e & 63] = a[j];
    }
    __syncthreads();
    if (tid < 256) {
      const int p = tid >> 4, seg = (tid & 15) << 2;
      float rs = 0.f;
      #pragma unroll
      for (int n = 0; n < 4; ++n) rs += srow[p][seg + n] + 0.001f;
      #pragma unroll
      for (int m = 1; m < 16; m <<= 1) rs += __shfl_xor(rs, m);
      float inv = 1.0f / (rs + 1e-8f);
      float h = 0.f;
      #pragma unroll
      for (int n = 0; n < 4; ++n) {
        float T = (srow[p][seg + n] + 0.001f) * inv;
        h -= T * logf(T + 1e-8f);
      }
      #pragma unroll
      for (int m = 1; m < 16; m <<= 1) h += __shfl_xor(h, m);
      if ((tid & 15) == 0) hcond[k*64 + mq*16 + p] = h;
    }

    if (bx < 4) {
      const int p0 = bx * 1024;
      #pragma unroll
      for (int j = 0; j < 2; ++j) {
        int p = p0 + tid + j*512;
        float s = 0.f;
        #pragma unroll
        for (int cc = 0; cc < 16; ++cc) s += ppart[cc*4096 + p];
        Cpair[p] = s;
      }
    }
    if (bx == 4) {
      __syncthreads();
      const int t = tid & 63, part = w;
      float s = 0.f;
      for (int c2 = 0; c2 < 32; ++c2) s += ghist_part[((part*32 + c2) << 6) + t];
      hpart[part][t] = s;
      double ms = (tid < 256) ? gmse_part[tid] : 0.0;
      #pragma unroll
      for (int off = 32; off; off >>= 1) ms += __shfl_down(ms, off);
      if (t == 0) dred[part] = ms;
      __syncthreads();
      if (tid < 64) {
        float ss = 0.f;
        #pragma unroll
        for (int p2 = 0; p2 < 8; ++p2) ss += hpart[p2][tid];
        hsumg[tid] = ss;
      }
      if (tid == 64) {
        double m = 0.0;
        #pragma unroll
        for (int p2 = 0; p2 < 8; ++p2) m += dred[p2];
        gmseg[0] = m;
      }
    }
  }

  gbar(bar, 2);

  // ================= P4: final scalar =================
  if (bx == 0) {
    float* red = (float*)smem;   // [24]
    float ts = 0.f, hh = 0.f;
    for (int p = tid; p < 4096; p += 512) {
      float cp = Cpair[p];
      ts += cp; hh += cp * hcond[p];
    }
    #pragma unroll
    for (int off = 32; off; off >>= 1) {
      ts += __shfl_down(ts, off);
      hh += __shfl_down(hh, off);
    }
    if (lane == 0) { red[w] = ts; red[8 + w] = hh; }

    if (tid < 64) {
      float pk = hsumg[tid] * (1.0f / 16384.0f);
      float klp = pk * (logf(pk + 1e-10f) - logf(prior[tid] + 1e-10f));
      #pragma unroll
      for (int off = 32; off; off >>= 1) klp += __shfl_down(klp, off);
      if (tid == 0) red[16] = klp;
    }
    __syncthreads();
    if (tid == 0) {
      float total = 0.f, hsum = 0.f;
      #pragma unroll
      for (int j = 0; j < 8; ++j) { total += red[j]; hsum += red[8 + j]; }
      float H2 = hsum / (total + 1e-8f);
      float mse = (float)(gmseg[0] * (1.0 / (16384.0 * 128.0)));
      loss_out[0] = 1.25f * mse + red[16] + 0.1f * H2;
    }
  }
}

extern "C" void kernel_launch(void* const* d_in, const int* in_sizes, int n_in,
                              void* d_out, int out_size, void* d_ws, size_t ws_size,
                              hipStream_t stream)
{
  (void)in_sizes; (void)n_in; (void)out_size; (void)ws_size;
  const float* x     = (const float*)d_in[0];
  const float* emb   = (const float*)d_in[2];
  const float* prior = (const float*)d_in[3];
  float* quant    = (float*)d_out;
  float* loss_out = (float*)d_out + 2097152;

  char* ws = (char*)d_ws;
  unsigned short* qbf        = (unsigned short*)(ws);           // 6,291,456 B
  float*          cpart      = (float*)(ws + 6291456);          // 16,777,216 B
  float*          ppart      = (float*)(ws + 23068672);         // 262,144 B
  float*          ghist_part = (float*)(ws + 23330816);         // 65,536 B
  double*         gmse_part  = (double*)(ws + 23396352);        // 2,048 B
  float*          hcond      = (float*)(ws + 23398400);         // 16,384 B
  float*          Cpair      = (float*)(ws + 23414784);         // 16,384 B
  float*          hsumg      = (float*)(ws + 23431168);         // 256 B
  double*         gmseg      = (double*)(ws + 23431424);        // 8 B
  unsigned*       gbarrier   = (unsigned*)(ws + 23431488);      // 64 B

  hipMemsetAsync(gbarrier, 0, 64, stream);
  vq_fused<<<GRID, 512, 0, stream>>>(x, emb, prior, qbf, cpart, ppart,
                                     ghist_part, gmse_part, hcond, Cpair,
                                     hsumg, gmseg, gbarrier, quant, loss_out);
}

// Round 21
// 87.470 us; speedup vs baseline: 2.9432x; 2.9432x over previous
//
#include <hip/hip_runtime.h>
#include <cstdint>

#define NROWS 16384

typedef __attribute__((ext_vector_type(4))) float f32x4;
typedef _Float16 half8 __attribute__((ext_vector_type(8)));
typedef unsigned int u32x4 __attribute__((ext_vector_type(4)));

static __device__ __forceinline__ void gl_lds16(const void* g, void* l) {
  __builtin_amdgcn_global_load_lds(
      (const __attribute__((address_space(1))) unsigned int*)g,
      (__attribute__((address_space(3))) unsigned int*)l, 16, 0, 0);
}

// ---------------- k1: distances/argmin/softmax/quantize + fp16 image build ----------------
__global__ __launch_bounds__(512) void vq_k1(
    const float* __restrict__ x, const float* __restrict__ emb,
    unsigned short* __restrict__ qbf, float* __restrict__ quant,
    float* __restrict__ ghist_part, double* __restrict__ gmse_part)
{
  __shared__ float Et4[32][64][4];
  __shared__ float xs[8][4][128];
  __shared__ float qlds[66][65];
  __shared__ float lhist[64];
  __shared__ double mred[8];
  const int tid = threadIdx.x;
  const int w = tid >> 6, lane = tid & 63;
  const int c = blockIdx.x;

  for (int i = tid; i < 2048; i += 512) {
    float4 v = ((const float4*)emb)[i];
    *(float4*)&Et4[i & 31][i >> 5][0] = v;
  }
  if (tid < 64) lhist[tid] = 0.0f;
  __syncthreads();

  double esq = 0.0;
  for (int g = 0; g < 32; ++g) {
    float4 e = *(float4*)&Et4[g][lane][0];
    esq += (double)e.x*e.x + (double)e.y*e.y + (double)e.z*e.z + (double)e.w*e.w;
  }
  const float esqf = (float)esq;

  double msea = 0.0;

  for (int it = 0; it < 3; ++it) {
    const int lr0 = it*32 + w*4;
    const bool act = (it < 2) || (w == 0);
    if (!act) continue;
    const int nr = (it < 2) ? 4 : 2;
    const int r0 = c*64 + lr0;
    const float4* xg = (const float4*)(x + (size_t)r0 * 128);
    if (it < 2) {
      float4 v0 = xg[lane], v1 = xg[lane + 64];
      *(float4*)&xs[w][lane>>5][(lane&31)<<2] = v0;
      *(float4*)&xs[w][2+(lane>>5)][(lane&31)<<2] = v1;
    } else {
      int rr = lane >> 5;
      float4 v0 = make_float4(0.f,0.f,0.f,0.f);
      if (r0 + rr < NROWS) v0 = xg[lane];
      *(float4*)&xs[w][rr][(lane&31)<<2] = v0;
    }

    float accf[4] = {0.f,0.f,0.f,0.f};
    for (int g = 0; g < 32; ++g) {
      float4 e = *(float4*)&Et4[g][lane][0];
      #pragma unroll
      for (int rr = 0; rr < 4; ++rr) {
        float4 xv = *(float4*)&xs[w][rr][g<<2];
        accf[rr] += e.x*xv.x + e.y*xv.y + e.z*xv.z + e.w*xv.w;
      }
    }

    for (int rr = 0; rr < nr; ++rr) {
      float dist = esqf - 2.0f*accf[rr];
      float mx = dist;
      #pragma unroll
      for (int off = 32; off; off >>= 1) mx = fmaxf(mx, __shfl_xor(mx, off));
      float sh = dist - mx;
      float ss = expf(sh);
      #pragma unroll
      for (int off = 32; off; off >>= 1) ss += __shfl_xor(ss, off);
      qlds[lr0 + rr][lane] = sh - logf(ss);

      if (it < 2) {
        float m1 = dist, m2 = 3.4e38f; int i1 = lane;
        #pragma unroll
        for (int off = 32; off; off >>= 1) {
          float om1 = __shfl_xor(m1, off);
          int   oi1 = __shfl_xor(i1, off);
          float om2 = __shfl_xor(m2, off);
          float nm2 = fminf(m2, om2);
          if (om1 < m1 || (om1 == m1 && oi1 < i1)) { nm2 = fminf(nm2, m1); m1 = om1; i1 = oi1; }
          else nm2 = fminf(nm2, om1);
          m2 = nm2;
        }
        int bi = i1;
        if (m2 - m1 < 1e-4f) {
          double a64 = 0.0;
          for (int g = 0; g < 32; ++g) {
            float4 e = *(float4*)&Et4[g][lane][0];
            float4 xv = *(float4*)&xs[w][rr][g<<2];
            a64 += (double)e.x*xv.x + (double)e.y*xv.y + (double)e.z*xv.z + (double)e.w*xv.w;
          }
          double v = esq - 2.0*a64; int b2 = lane;
          #pragma unroll
          for (int off = 32; off; off >>= 1) {
            double ov = __shfl_xor(v, off);
            int ob = __shfl_xor(b2, off);
            if (ov < v || (ov == v && ob < b2)) { v = ov; b2 = ob; }
          }
          bi = b2;
        }
        const int row = r0 + rr;
        float e0 = emb[bi*128 + lane], e1 = emb[bi*128 + 64 + lane];
        float x0 = xs[w][rr][lane], x1 = xs[w][rr][64 + lane];
        quant[(size_t)row*128 + lane]      = x0 + (e0 - x0);
        quant[(size_t)row*128 + 64 + lane] = x1 + (e1 - x1);
        double d0 = (double)e0 - x0, d1 = (double)e1 - x1;
        msea += d0*d0 + d1*d1;
        if (lane == 0) atomicAdd(&lhist[bi], 1.0f);
      }
    }
  }
  #pragma unroll
  for (int off = 32; off; off >>= 1) msea += __shfl_down(msea, off);
  if (lane == 0) mred[w] = msea;
  __syncthreads();
  if (tid == 0) {
    double s = 0.0;
    #pragma unroll
    for (int j = 0; j < 8; ++j) s += mred[j];
    gmse_part[c] = s;
  }
  if (tid < 64) ghist_part[(c << 6) + tid] = lhist[tid];

  char* out0 = (char*)qbf + (size_t)c * 24576;
  for (int idx = tid; idx < 1536; idx += 512) {
    int s = idx >> 9, kk = (idx >> 3) & 63, t8 = (idx & 7) << 3;
    union { _Float16 h[8]; uint4 u; } pk;
    #pragma unroll
    for (int j = 0; j < 8; ++j) {
      int tt = t8 + j, t = c*64 + tt;
      float val = qlds[tt + s][kk];
      bool zero = (s == 1 && (t & 4095) == 4095) || (s == 2 && (t & 4095) >= 4094);
      pk.h[j] = (_Float16)(zero ? 0.0f : val);
    }
    int off;
    if (s == 0) off = kk*128 + t8*2;
    else off = s*8192 + (((kk >> 4) << 1) + (t8 >> 5))*1024 + ((kk & 15) | (((t8 >> 3) & 3) << 4))*16;
    *(uint4*)(out0 + off) = pk.u;
  }
}

// ---------------- shared compute machinery ----------------
struct TR { u32x4 q0a, a0, a1, a2, a3, b0, b1, b2, b3,
                  q0b, c0, c1, c2, c3, d0, d1, d2, d3; };

#define WAITV(n) do { \
  asm volatile("s_waitcnt vmcnt(" #n ")" ::: "memory"); \
  __builtin_amdgcn_sched_barrier(0); \
} while (0)

#define MFMA4(avx, B0, B1, B2, B3, mb) do { \
  acc[mb][0] = __builtin_amdgcn_mfma_f32_16x16x32_f16(avx, __builtin_bit_cast(half8, B0), acc[mb][0], 0, 0, 0); \
  acc[mb][1] = __builtin_amdgcn_mfma_f32_16x16x32_f16(avx, __builtin_bit_cast(half8, B1), acc[mb][1], 0, 0, 0); \
  acc[mb][2] = __builtin_amdgcn_mfma_f32_16x16x32_f16(avx, __builtin_bit_cast(half8, B2), acc[mb][2], 0, 0, 0); \
  acc[mb][3] = __builtin_amdgcn_mfma_f32_16x16x32_f16(avx, __builtin_bit_cast(half8, B3), acc[mb][3], 0, 0, 0); \
} while (0)

#define COMPUTE2(T) do { \
  half8 _q0 = __builtin_bit_cast(half8, T.q0a); \
  half8 _av; \
  _av = _q0 * __builtin_bit_cast(half8, T.a0); MFMA4(_av, T.b0, T.b1, T.b2, T.b3, 0); \
  _av = _q0 * __builtin_bit_cast(half8, T.a1); MFMA4(_av, T.b0, T.b1, T.b2, T.b3, 1); \
  _av = _q0 * __builtin_bit_cast(half8, T.a2); MFMA4(_av, T.b0, T.b1, T.b2, T.b3, 2); \
  _av = _q0 * __builtin_bit_cast(half8, T.a3); MFMA4(_av, T.b0, T.b1, T.b2, T.b3, 3); \
  _q0 = __builtin_bit_cast(half8, T.q0b); \
  _av = _q0 * __builtin_bit_cast(half8, T.c0); MFMA4(_av, T.d0, T.d1, T.d2, T.d3, 0); \
  _av = _q0 * __builtin_bit_cast(half8, T.c1); MFMA4(_av, T.d0, T.d1, T.d2, T.d3, 1); \
  _av = _q0 * __builtin_bit_cast(half8, T.c2); MFMA4(_av, T.d0, T.d1, T.d2, T.d3, 2); \
  _av = _q0 * __builtin_bit_cast(half8, T.c3); MFMA4(_av, T.d0, T.d1, T.d2, T.d3, 3); \
  __builtin_amdgcn_sched_barrier(0); \
} while (0)

#define DECL_VOFFS_LIN \
  const int lf = lane * 16; \
  const int voff_q0a = (k << 7) + ((lane >> 4) << 4); \
  const int voff_q0b = voff_q0a + 64; \
  const int voff_a0 = 8192  + 0*2048 + lf; \
  const int voff_a1 = 8192  + 1*2048 + lf; \
  const int voff_a2 = 8192  + 2*2048 + lf; \
  const int voff_a3 = 8192  + 3*2048 + lf; \
  const int voff_b0 = 16384 + 0*2048 + lf; \
  const int voff_b1 = 16384 + 1*2048 + lf; \
  const int voff_b2 = 16384 + 2*2048 + lf; \
  const int voff_b3 = 16384 + 3*2048 + lf; \
  const int voff_c0 = 8192  + 0*2048 + 1024 + lf; \
  const int voff_c1 = 8192  + 1*2048 + 1024 + lf; \
  const int voff_c2 = 8192  + 2*2048 + 1024 + lf; \
  const int voff_c3 = 8192  + 3*2048 + 1024 + lf; \
  const int voff_d0 = 16384 + 0*2048 + 1024 + lf; \
  const int voff_d1 = 16384 + 1*2048 + 1024 + lf; \
  const int voff_d2 = 16384 + 2*2048 + 1024 + lf; \
  const int voff_d3 = 16384 + 3*2048 + 1024 + lf;

// ---------------- k23c: C partials — gl_lds DMA staging + coalesced C-write ----------------
__global__ __launch_bounds__(256, 1) void vq_k23c(const unsigned short* __restrict__ qbf,
                                                  float* __restrict__ cpart)
{
  __shared__ __align__(16) char ldsb[98304];   // 4 x 24576
  const int bx = blockIdx.x;
  const int tid = threadIdx.x;
  const int w = tid >> 6, lane = tid & 63;
  const char* qb = (const char*)qbf;

  const int kg = bx >> 4, chunk = bx & 15;
  const int k = kg*4 + w;
  DECL_VOFFS_LIN

  f32x4 acc[4][4];
  #pragma unroll
  for (int i = 0; i < 4; ++i)
    #pragma unroll
    for (int j = 0; j < 4; ++j) acc[i][j] = (f32x4)(0.f);

  const int t0 = chunk * 16;

#define STAGE(t, b) do { \
  const char* _s = qb + (size_t)(t0 + (t)) * 24576 + tid*16; \
  char* _d = ldsb + (size_t)(b)*24576 + tid*16; \
  gl_lds16(_s + 0*4096, _d + 0*4096); \
  gl_lds16(_s + 1*4096, _d + 1*4096); \
  gl_lds16(_s + 2*4096, _d + 2*4096); \
  gl_lds16(_s + 3*4096, _d + 3*4096); \
  gl_lds16(_s + 4*4096, _d + 4*4096); \
  gl_lds16(_s + 5*4096, _d + 5*4096); \
} while (0)

#define LDSCOMP(b) do { \
  const char* _L = ldsb + (size_t)(b)*24576; \
  TR T; \
  T.q0a = *(const u32x4*)(_L + voff_q0a); \
  T.q0b = *(const u32x4*)(_L + voff_q0b); \
  T.a0  = *(const u32x4*)(_L + voff_a0); \
  T.a1  = *(const u32x4*)(_L + voff_a1); \
  T.a2  = *(const u32x4*)(_L + voff_a2); \
  T.a3  = *(const u32x4*)(_L + voff_a3); \
  T.b0  = *(const u32x4*)(_L + voff_b0); \
  T.b1  = *(const u32x4*)(_L + voff_b1); \
  T.b2  = *(const u32x4*)(_L + voff_b2); \
  T.b3  = *(const u32x4*)(_L + voff_b3); \
  T.c0  = *(const u32x4*)(_L + voff_c0); \
  T.c1  = *(const u32x4*)(_L + voff_c1); \
  T.c2  = *(const u32x4*)(_L + voff_c2); \
  T.c3  = *(const u32x4*)(_L + voff_c3); \
  T.d0  = *(const u32x4*)(_L + voff_d0); \
  T.d1  = *(const u32x4*)(_L + voff_d1); \
  T.d2  = *(const u32x4*)(_L + voff_d2); \
  T.d3  = *(const u32x4*)(_L + voff_d3); \
  COMPUTE2(T); \
} while (0)

#define STEP_MID(i) do { \
  STAGE((i)+2, ((i)+2)&3); \
  WAITV(12); \
  __builtin_amdgcn_s_barrier(); \
  LDSCOMP((i)&3); \
} while (0)

  STAGE(0, 0);
  STAGE(1, 1);

  STEP_MID(0);  STEP_MID(1);  STEP_MID(2);  STEP_MID(3);
  STEP_MID(4);  STEP_MID(5);  STEP_MID(6);  STEP_MID(7);
  STEP_MID(8);  STEP_MID(9);  STEP_MID(10); STEP_MID(11);
  STEP_MID(12); STEP_MID(13);

  WAITV(6);
  __builtin_amdgcn_s_barrier();
  LDSCOMP(14 & 3);
  WAITV(0);
  __builtin_amdgcn_s_barrier();
  LDSCOMP(15 & 3);

#undef STEP_MID
#undef LDSCOMP
#undef STAGE

  // ---- coalesced C-write: acc -> LDS (tile layout) -> 16x dwordx4/lane contiguous ----
  __syncthreads();   // staging buffers shared across waves; all reads done
  {
    float* lw = (float*)(ldsb + (size_t)w * 16384);   // 16KB per wave, 64KB total
    const int m0 = (lane >> 4) << 2, n0 = lane & 15;
    #pragma unroll
    for (int mb = 0; mb < 4; ++mb)
      #pragma unroll
      for (int nb = 0; nb < 4; ++nb)
        #pragma unroll
        for (int r = 0; r < 4; ++r)
          lw[(mb*16 + m0 + r)*64 + nb*16 + n0] = acc[mb][nb][r];
    f32x4* Ck4 = (f32x4*)(cpart + ((size_t)chunk*64 + (size_t)k) * 4096);
    const f32x4* ls4 = (const f32x4*)lw;
    #pragma unroll
    for (int j = 0; j < 16; ++j)
      Ck4[j*64 + lane] = ls4[j*64 + lane];
  }
}

// ---------------- k23p: C_pair partials ----------------
__global__ __launch_bounds__(256) void vq_k23p(const unsigned short* __restrict__ qbf,
                                               float* __restrict__ ppart)
{
  __shared__ float redf[4096];
  const int bx2 = blockIdx.x;
  const int tid = threadIdx.x;
  const int w = tid >> 6, lane = tid & 63;
  const char* qb = (const char*)qbf;
  for (int i = tid; i < 4096; i += 256) redf[i] = 0.f;

  f32x4 acc[4][4];
  #pragma unroll
  for (int i = 0; i < 4; ++i)
    #pragma unroll
    for (int j = 0; j < 4; ++j) acc[i][j] = (f32x4)(0.f);

  for (int ii = 0; ii < 4; ++ii) {
    const char* tp = qb + (size_t)(bx2*16 + w*4 + ii) * 24576;
    #pragma unroll
    for (int s = 0; s < 2; ++s) {
      half8 Av[4], Bv[4];
      #pragma unroll
      for (int mb = 0; mb < 4; ++mb)
        Av[mb] = *(const half8*)(tp + (mb*16 + (lane & 15))*128 + ((lane >> 4) << 4) + s*64);
      #pragma unroll
      for (int nb = 0; nb < 4; ++nb)
        Bv[nb] = *(const half8*)(tp + 8192 + (nb*2 + s)*1024 + lane*16);
      #pragma unroll
      for (int mb = 0; mb < 4; ++mb)
        #pragma unroll
        for (int nb = 0; nb < 4; ++nb)
          acc[mb][nb] = __builtin_amdgcn_mfma_f32_16x16x32_f16(Av[mb], Bv[nb], acc[mb][nb], 0, 0, 0);
    }
  }
  __syncthreads();
  const int m0 = (lane >> 4) << 2, n0 = lane & 15;
  #pragma unroll
  for (int mb = 0; mb < 4; ++mb)
    #pragma unroll
    for (int nb = 0; nb < 4; ++nb)
      #pragma unroll
      for (int r = 0; r < 4; ++r)
        atomicAdd(&redf[(mb*16 + m0 + r)*64 + nb*16 + n0], acc[mb][nb][r]);
  __syncthreads();
  float* dst = ppart + (size_t)bx2 * 4096;
  for (int i = tid; i < 4096; i += 256) dst[i] = redf[i];
}

// ---------------- k45: hcond rows (0..255) + Cpair reduce (256..259) + hist/mse (260) ----------------
__global__ __launch_bounds__(256) void vq_k45(const float* __restrict__ cpart, const float* __restrict__ ppart,
                                              const float* __restrict__ ghist_part, const double* __restrict__ gmse_part,
                                              float* __restrict__ hcond, float* __restrict__ Cpair,
                                              float* __restrict__ hsumg, double* __restrict__ gmseg)
{
  const int bx = blockIdx.x, tid = threadIdx.x;
  if (bx < 256) {
    __shared__ float srow[16][68];
    const int k = bx >> 2, mq = bx & 3;
    f32x4 a = (f32x4)(0.f);
    #pragma unroll
    for (int cc = 0; cc < 16; ++cc)
      a += ((const f32x4*)(cpart + (size_t)cc*262144 + (size_t)k*4096 + mq*1024))[tid];
    *(f32x4*)&srow[tid >> 4][(tid & 15) << 2] = a;
    __syncthreads();
    const int p = tid >> 4, seg = (tid & 15) << 2;
    float rs = 0.f;
    #pragma unroll
    for (int n = 0; n < 4; ++n) rs += srow[p][seg + n] + 0.001f;
    #pragma unroll
    for (int m = 1; m < 16; m <<= 1) rs += __shfl_xor(rs, m);
    float inv = 1.0f / (rs + 1e-8f);
    float h = 0.f;
    #pragma unroll
    for (int n = 0; n < 4; ++n) {
      float T = (srow[p][seg + n] + 0.001f) * inv;
      h -= T * logf(T + 1e-8f);
    }
    #pragma unroll
    for (int m = 1; m < 16; m <<= 1) h += __shfl_xor(h, m);
    if ((tid & 15) == 0) hcond[k*64 + mq*16 + p] = h;
  } else if (bx < 260) {
    const int p0 = (bx - 256) * 1024;
    #pragma unroll
    for (int j = 0; j < 4; ++j) {
      int p = p0 + tid + j*256;
      float s = 0.f;
      #pragma unroll
      for (int cc = 0; cc < 16; ++cc) s += ppart[cc*4096 + p];
      Cpair[p] = s;
    }
  } else {
    __shared__ float hpart[4][64];
    __shared__ double dred[4];
    const int t = tid & 63, part = tid >> 6;
    float s = 0.f;
    for (int c2 = 0; c2 < 64; ++c2) s += ghist_part[((part*64 + c2) << 6) + t];
    hpart[part][t] = s;
    double ms = gmse_part[tid];
    #pragma unroll
    for (int off = 32; off; off >>= 1) ms += __shfl_down(ms, off);
    if (t == 0) dred[part] = ms;
    __syncthreads();
    if (tid < 64) hsumg[tid] = hpart[0][tid] + hpart[1][tid] + hpart[2][tid] + hpart[3][tid];
    if (tid == 64) gmseg[0] = dred[0] + dred[1] + dred[2] + dred[3];
  }
}

// ---------------- k5b: final scalar — fully lane-parallel ----------------
__global__ __launch_bounds__(256) void vq_k5b(const float* __restrict__ Cpair, const float* __restrict__ hcond,
                                              const float* __restrict__ hsumg, const double* __restrict__ gmseg,
                                              const float* __restrict__ prior, float* __restrict__ out_loss)
{
  __shared__ float red[12];
  const int tid = threadIdx.x;
  float ts = 0.f, hh = 0.f;
  for (int p = tid; p < 4096; p += 256) {
    float cp = Cpair[p];
    ts += cp; hh += cp * hcond[p];
  }
  #pragma unroll
  for (int off = 32; off; off >>= 1) {
    ts += __shfl_down(ts, off);
    hh += __shfl_down(hh, off);
  }
  if ((tid & 63) == 0) { red[tid >> 6] = ts; red[4 + (tid >> 6)] = hh; }

  if (tid < 64) {
    float pk = hsumg[tid] * (1.0f / 16384.0f);
    float klp = pk * (logf(pk + 1e-10f) - logf(prior[tid] + 1e-10f));
    #pragma unroll
    for (int off = 32; off; off >>= 1) klp += __shfl_down(klp, off);
    if (tid == 0) red[8] = klp;
  }
  __syncthreads();
  if (tid == 0) {
    float total = red[0] + red[1] + red[2] + red[3];
    float H2 = (red[4] + red[5] + red[6] + red[7]) / (total + 1e-8f);
    float mse = (float)(gmseg[0] * (1.0 / (16384.0 * 128.0)));
    out_loss[0] = 1.25f * mse + red[8] + 0.1f * H2;
  }
}

extern "C" void kernel_launch(void* const* d_in, const int* in_sizes, int n_in,
                              void* d_out, int out_size, void* d_ws, size_t ws_size,
                              hipStream_t stream)
{
  (void)in_sizes; (void)n_in; (void)out_size; (void)ws_size;
  const float* x     = (const float*)d_in[0];
  const float* emb   = (const float*)d_in[2];
  const float* prior = (const float*)d_in[3];
  float* quant    = (float*)d_out;
  float* loss_out = (float*)d_out + 2097152;

  char* ws = (char*)d_ws;
  unsigned short* qbf        = (unsigned short*)(ws);           // 6,291,456 B
  float*          cpart      = (float*)(ws + 6291456);          // 16,777,216 B
  float*          ppart      = (float*)(ws + 23068672);         // 262,144 B
  float*          ghist_part = (float*)(ws + 23330816);         // 65,536 B
  double*         gmse_part  = (double*)(ws + 23396352);        // 2,048 B
  float*          hcond      = (float*)(ws + 23398400);         // 16,384 B
  float*          Cpair      = (float*)(ws + 23414784);         // 16,384 B
  float*          hsumg      = (float*)(ws + 23431168);         // 256 B
  double*         gmseg      = (double*)(ws + 23431424);        // 8 B

  vq_k1  <<<256, 512, 0, stream>>>(x, emb, qbf, quant, ghist_part, gmse_part);
  vq_k23c<<<256, 256, 0, stream>>>(qbf, cpart);
  vq_k23p<<<16,  256, 0, stream>>>(qbf, ppart);
  vq_k45 <<<261, 256, 0, stream>>>(cpart, ppart, ghist_part, gmse_part, hcond, Cpair, hsumg, gmseg);
  vq_k5b <<<1,   256, 0, stream>>>(Cpair, hcond, hsumg, gmseg, prior, loss_out);
}